// Round 1
// baseline (559.697 us; speedup 1.0000x reference)
//
#include <hip/hip_runtime.h>

// FieldAwareFactorizationMachine (actually plain FM with per-field tables)
// x:   (16384, 20) int32   indices in [0, 100000)
// emb: (20, 100000, 64) float32
// out: (16384,) float32 = sum(x,axis=1) + 0.5*(||sum_f v_f||^2 - sum_f ||v_f||^2)

constexpr int BATCH = 16384;
constexpr int NUM_FIELDS = 20;
constexpr int NUM_FEATURES = 100000;
constexpr int LATENT = 64;

// One wave (64 lanes) per batch row; lane d owns latent dim d.
// Block = 256 threads = 4 rows per block.
__global__ __launch_bounds__(256)
void ffm_kernel(const int* __restrict__ x,
                const float* __restrict__ emb,
                float* __restrict__ out) {
    const int wave_in_block = threadIdx.x >> 6;
    const int lane          = threadIdx.x & 63;
    const int row           = blockIdx.x * 4 + wave_in_block;
    if (row >= BATCH) return;

    const int* xr = x + row * NUM_FIELDS;

    float s    = 0.0f;   // per-dim sum over fields
    float sq   = 0.0f;   // per-dim sum of squares over fields
    float xsum = 0.0f;   // linear term (same in every lane)

#pragma unroll
    for (int f = 0; f < NUM_FIELDS; ++f) {
        const int idx = xr[f];                       // wave-uniform broadcast load
        xsum += (float)idx;
        // offset fits in 32 bits: max (19*100000+99999)*64+63 = 127,999,999
        const int off = (f * NUM_FEATURES + idx) * LATENT + lane;
        const float v = emb[off];                    // 64 lanes -> 256B coalesced
        s  += v;
        sq += v * v;
    }

    float t = 0.5f * (s * s - sq);

    // wave-wide sum over 64 lanes
#pragma unroll
    for (int off = 32; off > 0; off >>= 1)
        t += __shfl_down(t, off, 64);

    if (lane == 0)
        out[row] = xsum + t;
}

extern "C" void kernel_launch(void* const* d_in, const int* in_sizes, int n_in,
                              void* d_out, int out_size, void* d_ws, size_t ws_size,
                              hipStream_t stream) {
    const int*   x   = (const int*)d_in[0];
    // d_in[1] = field_indices (arange(20)) — unused, gather order is implicit
    const float* emb = (const float*)d_in[2];
    float*       out = (float*)d_out;

    const int rows_per_block = 4;                 // 256 threads / 64 lanes
    const int grid = (BATCH + rows_per_block - 1) / rows_per_block;
    ffm_kernel<<<grid, 256, 0, stream>>>(x, emb, out);
}